// Round 19
// baseline (554.294 us; speedup 1.0000x reference)
//
#include <hip/hip_runtime.h>
#include <hip/hip_bf16.h>

#define FDIM 200
#define BB   128
#define LL   256
#define NN   8
#define BL   (BB*LL)
#define AOUTD 39
#define BOUTD 10
#define KCH  28            // K chunks of 8 elems (224 = 7 MFMA steps x 32)

// chunk-major weight panels (16B chunk index bases)
#define P1C 0              // mol ctx (maw_n)  Ng=256        -> 7168
#define PMG 7168           // mol gi|gh pair   Ng=1536       -> 50176
#define PA0 50176          // rd0 S|P|Q        Ng=640        -> 68096
#define PG0 68096          // rd0 pair         Ng=1536       -> 111104
#define PA1 111104         // rd1 S|P|Q        Ng=640        -> 129024
#define PG1 129024         // rd1 pair         Ng=1536       -> 172032
#define PD  172032         // dec AL|U|V       Ng=128        -> 175616
#define WCHUNKS 175616
#define NBIAS 4864         // f32 bias-column table entries

typedef short v8s __attribute__((ext_vector_type(8)));
typedef float v4f __attribute__((ext_vector_type(4)));

// ---------- dtype helpers (runtime bf16-vs-f32 mode for INPUT tensors) ----------
__device__ __forceinline__ float bf2f(unsigned short u){
  union { unsigned int i; float f; } v; v.i = ((unsigned int)u) << 16; return v.f;
}
__device__ __forceinline__ unsigned short f2bf(float f){
  unsigned int x = __float_as_uint(f);
  x += 0x7fffu + ((x >> 16) & 1u);   // RNE
  return (unsigned short)(x >> 16);
}
__device__ __forceinline__ float ldf(const void* p, long long i, bool bf){
  return bf ? bf2f(((const unsigned short*)p)[i]) : ((const float*)p)[i];
}
__device__ __forceinline__ void stf(void* p, size_t i, float v, bool bf){
  if (bf) ((unsigned short*)p)[i] = f2bf(v);
  else    ((float*)p)[i] = v;
}
__device__ __forceinline__ float bflo(unsigned int q){
  union { unsigned int i; float f; } v; v.i = q << 16; return v.f;
}
__device__ __forceinline__ float bfhi(unsigned int q){
  union { unsigned int i; float f; } v; v.i = q & 0xffff0000u; return v.f;
}
__device__ __forceinline__ void ld8(const unsigned short* p, float* o){
  uint4 q = *(const uint4*)p;
  o[0]=bflo(q.x); o[1]=bfhi(q.x); o[2]=bflo(q.y); o[3]=bfhi(q.y);
  o[4]=bflo(q.z); o[5]=bfhi(q.z); o[6]=bflo(q.w); o[7]=bfhi(q.w);
}
__device__ __forceinline__ void ld8g(const void* p, size_t i, bool bf, float* o){
  if (bf){ ld8((const unsigned short*)p + i, o); }
  else {
    const float4* q = (const float4*)((const float*)p + i);
    float4 x = q[0], y = q[1];
    o[0]=x.x; o[1]=x.y; o[2]=x.z; o[3]=x.w;
    o[4]=y.x; o[5]=y.y; o[6]=y.z; o[7]=y.w;
  }
}
__device__ __forceinline__ void st8(unsigned short* p, const float* v){
  uint4 q;
  q.x = (unsigned int)f2bf(v[0]) | ((unsigned int)f2bf(v[1]) << 16);
  q.y = (unsigned int)f2bf(v[2]) | ((unsigned int)f2bf(v[3]) << 16);
  q.z = (unsigned int)f2bf(v[4]) | ((unsigned int)f2bf(v[5]) << 16);
  q.w = (unsigned int)f2bf(v[6]) | ((unsigned int)f2bf(v[7]) << 16);
  *(uint4*)p = q;
}
// dot of a 200-long input row with f32 LDS x[200]
__device__ __forceinline__ float dotF(const void* wp, size_t off, const float* x, bool bf){
  float a0=0.f,a1=0.f,a2=0.f,a3=0.f;
  if (bf){
    const uint4* p = (const uint4*)((const unsigned short*)wp + off);
#pragma unroll
    for (int c = 0; c < FDIM/8; ++c){
      uint4 q = p[c];
      const float* xb = x + c*8;
      a0 += bflo(q.x)*xb[0]; a1 += bfhi(q.x)*xb[1];
      a2 += bflo(q.y)*xb[2]; a3 += bfhi(q.y)*xb[3];
      a0 += bflo(q.z)*xb[4]; a1 += bfhi(q.z)*xb[5];
      a2 += bflo(q.w)*xb[6]; a3 += bfhi(q.w)*xb[7];
    }
  } else {
    const float4* p = (const float4*)((const float*)wp + off);
#pragma unroll
    for (int c = 0; c < FDIM/4; ++c){
      float4 q = p[c];
      const float* xb = x + c*4;
      a0 += q.x*xb[0]; a1 += q.y*xb[1]; a2 += q.z*xb[2]; a3 += q.w*xb[3];
    }
  }
  return (a0+a1)+(a2+a3);
}
__device__ __forceinline__ float sigm(float x){ return 1.f/(1.f+__expf(-x)); }
__device__ __forceinline__ float tanh_(float x){
  float cx = fminf(fmaxf(x, -15.f), 15.f);
  float e = __expf(2.f*cx);
  return (e - 1.f)/(e + 1.f);
}
__device__ __forceinline__ float elu_(float x){ return x > 0.f ? x : __expf(x) - 1.f; }

// ---------- dtype probe: atom_mask is all 1.0 ----------
__global__ void k_probe(const unsigned int* __restrict__ amask, int* __restrict__ mode){
  if (blockIdx.x == 0 && threadIdx.x == 0)
    *mode = (amask[0] == 0x3F803F80u) ? 1 : 0;
}

// ---------- weight repack -> chunk-major bf16 panels: chunk idx = base + c*Ng + n ----------
__global__ __launch_bounds__(256) void k_repack(unsigned short* __restrict__ wrep,
    const void* maw, const void* mwih, const void* mwhh,
    const void* alw, const void* atw, const void* gwih, const void* gwhh,
    const void* afw, const void* bfw, const int* __restrict__ mode){
  const bool bf = (*mode != 0);
  int idx = blockIdx.x*256 + threadIdx.x;
  if (idx >= WCHUNKS) return;
  int pb, Ng, kind; long long d = 0;     // kind: 0 ctx, 1 pair-mol, 2 spq, 3 pair-attn, 4 dec
  if (idx < PMG)      { pb = P1C; Ng = 256;  kind = 0; }
  else if (idx < PA0) { pb = PMG; Ng = 1536; kind = 1; }
  else if (idx < PG0) { pb = PA0; Ng = 640;  kind = 2; d = 0; }
  else if (idx < PA1) { pb = PG0; Ng = 1536; kind = 3; d = 0; }
  else if (idx < PG1) { pb = PA1; Ng = 640;  kind = 2; d = 1; }
  else if (idx < PD)  { pb = PG1; Ng = 1536; kind = 3; d = 1; }
  else                { pb = PD;  Ng = 128;  kind = 4; }
  int li = idx - pb;
  int c = li / Ng, n = li - c*Ng;
  const void* S = nullptr; long long sb = 0; int rl = 0, off = 0, row = 0;
  if (kind == 0){ if (n < 200){ S = maw; rl = 400; off = 200; row = n; } }
  else if (kind == 1 || kind == 3){
    int slot = n >> 8, f = n & 255;
    if (f < 200){
      int gate = (slot < 3) ? slot : slot - 3;
      if (kind == 1) S = (slot < 3) ? mwih : mwhh;
      else         { S = (slot < 3) ? gwih : gwhh; sb = d*120000; }
      rl = 200; row = gate*200 + f;
    }
  }
  else if (kind == 2){
    if (n < 200)      { S = alw; sb = d*80000; rl = 400; off = 0;   row = n; }
    else if (n < 400) { S = alw; sb = d*80000; rl = 400; off = 200; row = n-200; }
    else if (n < 600) { S = atw; sb = d*40000; rl = 200; off = 0;   row = n-400; }
  } else {
    if (n < 39)                { S = afw; rl = 200; row = n; }
    else if (n >= 40 && n < 50){ S = bfw; rl = 400; off = 0;   row = n-40; }
    else if (n >= 50 && n < 60){ S = bfw; rl = 400; off = 200; row = n-50; }
  }
  float v[8];
#pragma unroll
  for (int j = 0; j < 8; j++){
    int k = c*8 + j;
    v[j] = (S && k < 200) ? ldf(S, sb + (long long)row*rl + off + k, bf) : 0.f;
  }
  st8(wrep + (size_t)idx*8, v);
}

// ---------- bias-column table (f32) — layout unchanged ----------
__global__ __launch_bounds__(256) void k_biases(float* __restrict__ bt,
    const void* mbhh, const void* mbih, const void* alb, const void* atb,
    const void* gbhh, const void* gbih, const void* afb, const void* bfb,
    const int* __restrict__ mode){
  const bool bf = (*mode != 0);
  int e = blockIdx.x*256 + threadIdx.x;
  if (e >= NBIAS) return;
  float v = 0.f;
  if (e < 600)        v = ldf(mbhh, e, bf);
  else if (e < 1200)  v = ldf(mbih, e-600, bf);
  else if (e < 4800){
    int q = e - 1200; int d = q / 1800; q -= d*1800;
    if (q < 1200){
      if (q < 200)      v = ldf(alb, (long long)d*200 + q, bf);
      else if (q < 400) v = 0.f;
      else if (q < 600) v = ldf(atb, (long long)d*200 + q-400, bf);
      else              v = ldf(gbhh, (long long)d*600 + q-600, bf);
    } else              v = ldf(gbih, (long long)d*600 + q-1200, bf);
  } else {
    int q = e - 4800;
    if (q < 39)                 v = ldf(afb, q, bf);
    else if (q >= 40 && q < 50) v = ldf(bfb, q-40, bf);
  }
  bt[e] = v;
}

// ---------- GEMM: W-in-LDS 128x64 tile + XCD swizzle + LDS-transpose epilogue ----------
// emode: 0 plain | 1 acc+=bias[col] | 2 elu(pre_row[col]+acc)
__global__ __launch_bounds__(256, 5) void k_gemm(
    const unsigned short* __restrict__ A,
    const unsigned short* __restrict__ Wc, int wNg, int npan,
    unsigned short* __restrict__ C, int ldc, int Nout,
    int emode, const float* __restrict__ bias, int gbase)
{
  __shared__ unsigned short Ws[KCH*64*8];     // 28,672 B -> 5 blocks/CU
  int t = threadIdx.x;
  int bid = blockIdx.x;
  int res = bid & 7, q = bid >> 3;
  int p = q % npan;
  int mt = (q / npan)*8 + res;
  int nbase = p * 64;
  int mbase = mt * 128;
  const uint4* Wg = (const uint4*)Wc;
  uint4* Wl = (uint4*)Ws;
  for (int i = t; i < KCH*64; i += 256){      // linear LDS write: conflict-free
    int c = i >> 6, n = i & 63;
    Wl[i] = Wg[(size_t)c*wNg + nbase + n];
  }
  __syncthreads();
  int wave = t >> 6, lane = t & 63;
  int quad = lane >> 4, l16 = lane & 15;
  const unsigned short* A0 = A + (size_t)(mbase + wave*32 + l16)*FDIM + quad*8;
  v4f acc[2][4];
#pragma unroll
  for (int ms = 0; ms < 2; ms++)
#pragma unroll
    for (int ns = 0; ns < 4; ns++) acc[ms][ns] = (v4f){0.f,0.f,0.f,0.f};
#pragma unroll
  for (int ks = 0; ks < 7; ks++){
    v8s a0 = *(const v8s*)(A0 + ks*32);              // k>=200 garbage x zero-W = 0
    v8s a1 = *(const v8s*)(A0 + 16*FDIM + ks*32);
    const unsigned short* Bp = Ws + ((ks*4 + quad)*64 + l16)*8;
#pragma unroll
    for (int ns = 0; ns < 4; ns++){
      v8s b = *(const v8s*)(Bp + ns*128);            // 16 lanes consecutive 16B: conflict-free
      acc[0][ns] = __builtin_amdgcn_mfma_f32_16x16x32_bf16(a0, b, acc[0][ns], 0, 0, 0);
      acc[1][ns] = __builtin_amdgcn_mfma_f32_16x16x32_bf16(a1, b, acc[1][ns], 0, 0, 0);
    }
  }
  // ---- LDS-transpose epilogue: acc -> Ws (stride 72) -> 16B coalesced stores ----
  __syncthreads();                            // all waves done reading W tile
  const float* pr = (emode == 2) ? (bias + (size_t)(((gbase + mbase) >> 8))*FDIM) : nullptr;
#pragma unroll
  for (int ms = 0; ms < 2; ms++){
#pragma unroll
    for (int ns = 0; ns < 4; ns++){
      int lcol = l16 + ns*16;                 // 0..63
      int col = nbase + lcol;
      float badd = (emode == 1 && col < Nout) ? bias[col] : 0.f;
      float pv   = (emode == 2) ? pr[col] : 0.f;
      int lrow = wave*32 + ms*16 + quad*4;    // + reg
#pragma unroll
      for (int reg = 0; reg < 4; reg++){
        float v = acc[ms][ns][reg] + badd;
        if (emode == 2) v = elu_(pv + v);
        Ws[(lrow + reg)*72 + lcol] = f2bf(v);
      }
    }
  }
  __syncthreads();
#pragma unroll
  for (int j = 0; j < 4; j++){
    int g = t + j*256;                        // 0..1023: 128 rows x 8 col-groups
    int row = g >> 3, cg = g & 7;
    int col = nbase + cg*8;
    if (col < Nout){                          // Nout % 8 == 0 for all shapes
      uint4 qv = *(const uint4*)(Ws + row*72 + cg*8);
      *(uint4*)(C + (size_t)(mbase + row)*ldc + col) = qv;
    }
  }
}

// ---------- FULLY-FUSED GRU, phase-split: 3 slots in LDS at a time ----------
// Phase 1: stage gi slots (0..2), MFMA vs ctx. Phase 2: re-stage gh slots (3..5),
// MFMA vs act. LDS 21,504 B -> 7 blocks/CU (vs 3). A-load count unchanged.
__global__ __launch_bounds__(256, 7) void k_gru2(
    const unsigned short* __restrict__ ctxA,
    const unsigned short* __restrict__ actS,
    unsigned short* __restrict__ actD,
    const unsigned short* __restrict__ Wc,
    const float* __restrict__ gib, const float* __restrict__ ghb,
    int dorelu)
{
  __shared__ unsigned short Ws[3*KCH*16*8];   // 21,504 B
  int t = threadIdx.x, bid = blockIdx.x;
  int res = bid & 7, q = bid >> 3;
  int p = q % 13;
  int mt = (q / 13)*8 + res;
  int f0 = p*16;
  int mbase = mt*128;
  const uint4* Wg = (const uint4*)Wc;
  uint4* Wl = (uint4*)Ws;
  int wave = t >> 6, lane = t & 63;
  int quad = lane >> 4, l16 = lane & 15;
  v4f acc[6][2];
#pragma unroll
  for (int s = 0; s < 6; s++)
#pragma unroll
    for (int ms = 0; ms < 2; ms++) acc[s][ms] = (v4f){0.f,0.f,0.f,0.f};

#pragma unroll
  for (int ph = 0; ph < 2; ph++){
    // stage 3 slots of this phase
    if (ph) __syncthreads();                  // all waves done reading phase-0 Ws
    for (int i = t; i < 3*KCH*16; i += 256){
      int s = i / (KCH*16), r2 = i - s*(KCH*16);
      int c = r2 >> 4, n = r2 & 15;
      Wl[i] = Wg[(size_t)c*1536 + (ph*3 + s)*256 + f0 + n];
    }
    __syncthreads();
    const unsigned short* Ax = (ph == 0 ? ctxA : actS)
                             + (size_t)(mbase + wave*32 + l16)*FDIM + quad*8;
#pragma unroll
    for (int ks = 0; ks < 7; ks++){
      v8s x0 = *(const v8s*)(Ax + ks*32);
      v8s x1 = *(const v8s*)(Ax + 16*FDIM + ks*32);
#pragma unroll
      for (int s = 0; s < 3; s++){
        v8s b = *(const v8s*)(Ws + ((size_t)(s*KCH + ks*4 + quad)*16 + l16)*8);
        acc[ph*3+s][0] = __builtin_amdgcn_mfma_f32_16x16x32_bf16(x0, b, acc[ph*3+s][0], 0, 0, 0);
        acc[ph*3+s][1] = __builtin_amdgcn_mfma_f32_16x16x32_bf16(x1, b, acc[ph*3+s][1], 0, 0, 0);
      }
    }
  }
  int f = f0 + l16;
  if (f < 200){
    float bir = gib[f], biz = gib[200+f], bin = gib[400+f];
    float bhr = ghb[f], bhz = ghb[200+f], bhn = ghb[400+f];
#pragma unroll
    for (int ms = 0; ms < 2; ms++){
#pragma unroll
      for (int reg = 0; reg < 4; reg++){
        int row = mbase + wave*32 + ms*16 + quad*4 + reg;
        float h = bf2f(actS[(size_t)row*FDIM + f]);
        float r = sigm(acc[0][ms][reg] + bir + acc[3][ms][reg] + bhr);
        float z = sigm(acc[1][ms][reg] + biz + acc[4][ms][reg] + bhz);
        float n = tanh_(acc[2][ms][reg] + bin + r*(acc[5][ms][reg] + bhn));
        float hn = (1.f - z)*n + z*h;
        if (dorelu) hn = fmaxf(hn, 0.f);
        actD[(size_t)row*FDIM + f] = f2bf(hn);
      }
    }
  }
}

// ---------- pre_mol[b,f] = mab[f] + dot(mol[b], maw[f, :F]) ----------
__global__ __launch_bounds__(256) void k_premol(float* __restrict__ pre,
    const void* __restrict__ molf, const void* __restrict__ maw,
    const void* __restrict__ mab, const int* __restrict__ mode){
  const bool bf = (*mode != 0);
  int b = blockIdx.x, t = threadIdx.x;
  __shared__ float mf[FDIM];
  for (int f = t; f < FDIM; f += 256) mf[f] = ldf(molf, (size_t)b*FDIM+f, bf);
  __syncthreads();
  for (int f = t; f < FDIM; f += 256)
    pre[b*FDIM+f] = ldf(mab, f, bf) + dotF(maw, (size_t)f*2*FDIM, mf, bf);
}

// ---------- mw[b,l] = softmax_l(dot(act[b,l], mol[b])) ----------
__global__ __launch_bounds__(LL) void k_gitdot(float* __restrict__ mw_out,
    const void* __restrict__ molf, const void* __restrict__ actf,
    const int* __restrict__ mode){
  const bool bf = (*mode != 0);
  int b = blockIdx.x, l = threadIdx.x;
  __shared__ float mf[FDIM];
  __shared__ float red[LL];
  for (int f = l; f < FDIM; f += LL) mf[f] = ldf(molf, (size_t)b*FDIM+f, bf);
  __syncthreads();
  float d = dotF(actf, ((size_t)b*LL + l)*FDIM, mf, bf);
  red[l] = d; __syncthreads();
  for (int s = 128; s > 0; s >>= 1){ if (l < s) red[l] = fmaxf(red[l], red[l+s]); __syncthreads(); }
  float m = red[0]; __syncthreads();
  float e = __expf(d - m);
  red[l] = e; __syncthreads();
  for (int s = 128; s > 0; s >>= 1){ if (l < s) red[l] += red[l+s]; __syncthreads(); }
  mw_out[(size_t)b*LL + l] = e / red[0];
}

// ---------- act[row,f] = mw[row]*mol[b,f] + actf[row,f] ----------
__global__ __launch_bounds__(256) void k_gitwrite(unsigned short* __restrict__ act,
    const void* __restrict__ molf, const void* __restrict__ actf,
    const float* __restrict__ mw, const int* __restrict__ mode){
  const bool bf = (*mode != 0);
  int idx = blockIdx.x*256 + threadIdx.x;
  if (idx >= BL*25) return;
  int row = idx/25, f0 = (idx - row*25)*8;
  int b = row >> 8;
  float m = mw[row];
  float mv[8], av[8], v[8];
  ld8g(molf, (size_t)b*FDIM + f0, bf, mv);
  ld8g(actf, (size_t)row*FDIM + f0, bf, av);
#pragma unroll
  for (int j = 0; j < 8; j++) v[j] = m*mv[j] + av[j];
  st8(act + (size_t)row*FDIM + f0, v);
}

// ---------- attention elementwise, 8-wide: big[S'|P|Q'] stride 600 -> ctx ----------
__global__ __launch_bounds__(256) void k_attn_ew(const unsigned short* __restrict__ big,
    unsigned short* __restrict__ ctx, const int* __restrict__ adeg,
    int base, int total){
  int idx = blockIdx.x*256 + threadIdx.x;
  if (idx >= total) return;
  int a = idx/25, f0 = (idx - a*25)*8;
  int mb = (a >> 8) << 8;
  float s0[8];
  ld8(big + (size_t)a*600 + f0, s0);
  int4 d0 = *(const int4*)(adeg + (size_t)(base + a)*NN);
  int4 d1 = *(const int4*)(adeg + (size_t)(base + a)*NN + 4);
  int iv[NN] = {d0.x, d0.y, d0.z, d0.w, d1.x, d1.y, d1.z, d1.w};
  int nid[NN]; float nmul[NN], nadd[NN];
#pragma unroll
  for (int n = 0; n < NN; n++){
    nid[n] = mb + iv[n];
    bool pad = (iv[n] == LL-1);
    nmul[n] = pad ? 0.f : 1.f;
    nadd[n] = pad ? -9e8f : 0.f;
  }
  float e[NN][8], mx[8];
#pragma unroll
  for (int j = 0; j < 8; j++) mx[j] = -1e30f;
#pragma unroll
  for (int n = 0; n < NN; n++){
    float p[8];
    ld8(big + (size_t)nid[n]*600 + 200 + f0, p);
#pragma unroll
    for (int j = 0; j < 8; j++){
      float s = s0[j] + p[j];
      s = s > 0.f ? s : 0.01f*s;
      s += nadd[n];
      e[n][j] = s;
      mx[j] = fmaxf(mx[j], s);
    }
  }
  float sum[8] = {0,0,0,0,0,0,0,0};
#pragma unroll
  for (int n = 0; n < NN; n++)
#pragma unroll
    for (int j = 0; j < 8; j++){ e[n][j] = __expf(e[n][j] - mx[j]); sum[j] += e[n][j]; }
  float acc[8] = {0,0,0,0,0,0,0,0};
#pragma unroll
  for (int n = 0; n < NN; n++){
    float q[8];
    ld8(big + (size_t)nid[n]*600 + 400 + f0, q);
#pragma unroll
    for (int j = 0; j < 8; j++) acc[j] += e[n][j]*nmul[n]*q[j];
  }
  float o[8];
#pragma unroll
  for (int j = 0; j < 8; j++) o[j] = elu_(acc[j]/sum[j]);
  st8(ctx + (size_t)a*FDIM + f0, o);
}

// ---------- merged decode: 4 atoms/block (biases pre-folded into big) ----------
__global__ __launch_bounds__(256) void k_dec(const unsigned short* __restrict__ big,
    const int* __restrict__ adeg, void* __restrict__ out, int base,
    const int* __restrict__ mode){
  const bool bf = (*mode != 0);
  const size_t obase = (size_t)BL*AOUTD;
  int sub = threadIdx.x >> 6, tl = threadIdx.x & 63;
  int a = blockIdx.x*4 + sub;
  __shared__ float al[4][40];
  __shared__ float sm[4][4], ss[4][4];
  const int lo[4] = {0,16,24,31}, hi[4] = {16,22,30,36};
  if (tl < AOUTD) al[sub][tl] = bf2f(big[(size_t)a*64 + tl]);
  __syncthreads();
  if (tl < 4){
    float m = -1e30f;
    for (int k = lo[tl]; k < hi[tl]; k++) m = fmaxf(m, al[sub][k]);
    float s = 0.f;
    for (int k = lo[tl]; k < hi[tl]; k++) s += __expf(al[sub][k]-m);
    sm[sub][tl] = m; ss[sub][tl] = s;
  }
  __syncthreads();
  if (tl < AOUTD){
    float v = 0.f;
#pragma unroll
    for (int g = 0; g < 4; g++)
      if (tl >= lo[g] && tl < hi[g]) v += __expf(al[sub][tl]-sm[sub][g])/ss[sub][g];
    if (tl == 24) v += fmaxf(al[sub][24], 0.f);
    if (tl == 30 || tl == 36 || tl == 37 || tl == 38) v += sigm(al[sub][tl]);
    stf(out, (size_t)(base + a)*AOUTD + tl, v, bf);
  } else if (tl >= 40 && tl < 48){
    int n = tl - 40;
    int iv = adeg[((size_t)(base + a))*NN + n];
    int vr = ((a >> 8) << 8) + iv;
    float bl[BOUTD];
#pragma unroll
    for (int o = 0; o < BOUTD; o++)
      bl[o] = bf2f(big[(size_t)a*64 + 40 + o]) + bf2f(big[(size_t)vr*64 + 50 + o]);
    float v[BOUTD];
    float m0 = fmaxf(fmaxf(bl[0],bl[1]), fmaxf(bl[2],bl[3]));
    float e0[4], s0 = 0.f;
#pragma unroll
    for (int j = 0; j < 4; j++){ e0[j] = __expf(bl[j]-m0); s0 += e0[j]; }
    float m1 = fmaxf(fmaxf(bl[6],bl[7]), fmaxf(bl[8],bl[9]));
    float e1[4], s1 = 0.f;
#pragma unroll
    for (int j = 0; j < 4; j++){ e1[j] = __expf(bl[6+j]-m1); s1 += e1[j]; }
#pragma unroll
    for (int j = 0; j < 4; j++) v[j] = e0[j]/s0;
    v[4] = sigm(bl[4]); v[5] = sigm(bl[5]);
#pragma unroll
    for (int j = 0; j < 4; j++) v[6+j] = e1[j]/s1;
    size_t op = obase + ((size_t)(base + a)*NN + n)*BOUTD;
#pragma unroll
    for (int j = 0; j < BOUTD; j++) stf(out, op + j, v[j], bf);
  }
}

extern "C" void kernel_launch(void* const* d_in, const int* in_sizes, int n_in,
                              void* d_out, int out_size, void* d_ws, size_t ws_size,
                              hipStream_t stream) {
  const int* adeg = (const int*)d_in[2];
  const void* amask = d_in[4];
  const void* molf = d_in[5];
  const void* actf = d_in[6];
  const void* afw = d_in[7];  const void* afb = d_in[8];
  const void* bfw = d_in[9];  const void* bfb = d_in[10];
  const void* alw = d_in[11]; const void* alb = d_in[12];
  const void* atw = d_in[13]; const void* atb = d_in[14];
  const void* gwih = d_in[15]; const void* gwhh = d_in[16];
  const void* gbih = d_in[17]; const void* gbhh = d_in[18];
  const void* maw = d_in[19]; const void* mab = d_in[20];
  const void* mwih = d_in[21]; const void* mwhh = d_in[22];
  const void* mbih = d_in[23]; const void* mbhh = d_in[24];

  // ---- ws layout: act0 | act1 | mw | pre | wrep | bt | mode | ctx[CH] | big[CH,600] ----
  char* w = (char*)d_ws;
  unsigned short* act0 = (unsigned short*)w;  w += (size_t)BL*FDIM*2;           // 13.11 MB
  unsigned short* act1 = (unsigned short*)w;  w += (size_t)BL*FDIM*2;           // 13.11 MB
  float*          mw   = (float*)w;           w += (size_t)BL*4;
  float*          pre  = (float*)w;           w += (size_t)BB*FDIM*4;
  unsigned short* wrep = (unsigned short*)w;  w += (size_t)WCHUNKS*16;          // 2.81 MB
  float*          bt   = (float*)w;           w += (size_t)NBIAS*4;
  int*            mode = (int*)w;             w += 16;
  size_t fixed = (size_t)(w - (char*)d_ws);
  int CH = 8192;
  if (ws_size >= fixed + (size_t)32768*1600) CH = 32768;
  else if (ws_size >= fixed + (size_t)16384*1600) CH = 16384;
  unsigned short* ctx = (unsigned short*)w;   w += (size_t)CH*FDIM*2;
  unsigned short* big = (unsigned short*)w;                                     // [CH][600]
  const int NCH = BL / CH;
  const int EWT = CH*25, EWB = EWT/256;
  const int GY = CH/128;           // row-tiles per chunk (divisible by 8)

  k_probe<<<1, 64, 0, stream>>>((const unsigned int*)amask, mode);
  k_repack<<<(WCHUNKS + 255)/256, 256, 0, stream>>>(wrep, maw, mwih, mwhh,
      alw, atw, gwih, gwhh, afw, bfw, mode);
  k_biases<<<(NBIAS + 255)/256, 256, 0, stream>>>(bt, mbhh, mbih, alb, atb,
      gbhh, gbih, afb, bfb, mode);
  k_premol<<<BB, 256, 0, stream>>>(pre, molf, maw, mab, mode);
  k_gitdot<<<BB, LL, 0, stream>>>(mw, molf, actf, mode);
  k_gitwrite<<<(BL*25 + 255)/256, 256, 0, stream>>>(act0, molf, actf, mw, mode);

  unsigned short* cur = act0;
  unsigned short* alt = act1;

  // ---- mol GRU x2: ctx GEMM -> fully-fused GRU (gi+gh+update) ----
  for (int ts = 0; ts < 2; ts++){
    for (int c = 0; c < NCH; c++){
      int base = c*CH;
      unsigned short* Ac = cur + (size_t)base*FDIM;
      k_gemm<<<4*GY, 256, 0, stream>>>(Ac, wrep + (size_t)P1C*8, 256, 4,
          ctx, FDIM, FDIM, 2, pre, base);                                       // ctx = elu(pre+.)
      k_gru2<<<13*GY, 256, 0, stream>>>(ctx, Ac, alt + (size_t)base*FDIM,
          wrep + (size_t)PMG*8, bt + 600, bt + 0, (ts==1));
    }
    { unsigned short* tmp = cur; cur = alt; alt = tmp; }
  }
  // ---- 2 attention+GRU rounds ----
  for (int d = 0; d < 2; d++){
    size_t pA = (d ? PA1 : PA0), pG = (d ? PG1 : PG0);
    float* btA = bt + 1200 + d*1800;          // alb|0|atb (600 entries)
    float* gib = bt + 2400 + d*1800;          // gbih
    float* ghb = bt + 1800 + d*1800;          // gbhh
    for (int c = 0; c < NCH; c++){
      int base = c*CH;
      unsigned short* Ac = cur + (size_t)base*FDIM;
      k_gemm<<<10*GY, 256, 0, stream>>>(Ac, wrep + pA*8, 640, 10,
          big, 600, 600, 1, btA, 0);                                            // S'|P|Q'
      k_attn_ew<<<EWB, 256, 0, stream>>>(big, ctx, adeg, base, EWT);
      k_gru2<<<13*GY, 256, 0, stream>>>(ctx, Ac, alt + (size_t)base*FDIM,
          wrep + pG*8, gib, ghb, 1);
    }
    { unsigned short* tmp = cur; cur = alt; alt = tmp; }
  }
  // ---- decode (cur == act0 after 4 swaps) ----
  for (int c = 0; c < NCH; c++){
    int base = c*CH;
    unsigned short* Ac = cur + (size_t)base*FDIM;
    k_gemm<<<1*GY, 256, 0, stream>>>(Ac, wrep + (size_t)PD*8, 128, 1,
        big, 64, 64, 1, bt + 4800, 0);                                          // AL|U|V (+afb,bfb)
    k_dec<<<CH/4, 256, 0, stream>>>(big, adeg, d_out, base, mode);
  }
}

// Round 20
// 516.169 us; speedup vs baseline: 1.0739x; 1.0739x over previous
//
#include <hip/hip_runtime.h>
#include <hip/hip_bf16.h>

#define FDIM 200
#define BB   128
#define LL   256
#define NN   8
#define BL   (BB*LL)
#define AOUTD 39
#define BOUTD 10
#define KCH  28            // K chunks of 8 elems (224 = 7 MFMA steps x 32)

// chunk-major weight panels (16B chunk index bases)
#define P1C 0              // mol ctx (maw_n)  Ng=256        -> 7168
#define PMG 7168           // mol gi|gh pair   Ng=1536       -> 50176
#define PA0 50176          // rd0 S|P|Q        Ng=640        -> 68096
#define PG0 68096          // rd0 pair         Ng=1536       -> 111104
#define PA1 111104         // rd1 S|P|Q        Ng=640        -> 129024
#define PG1 129024         // rd1 pair         Ng=1536       -> 172032
#define PD  172032         // dec AL|U|V       Ng=128        -> 175616
#define WCHUNKS 175616
#define NBIAS 4864         // f32 bias-column table entries

typedef short v8s __attribute__((ext_vector_type(8)));
typedef float v4f __attribute__((ext_vector_type(4)));

// ---------- dtype helpers (runtime bf16-vs-f32 mode for INPUT tensors) ----------
__device__ __forceinline__ float bf2f(unsigned short u){
  union { unsigned int i; float f; } v; v.i = ((unsigned int)u) << 16; return v.f;
}
__device__ __forceinline__ unsigned short f2bf(float f){
  unsigned int x = __float_as_uint(f);
  x += 0x7fffu + ((x >> 16) & 1u);   // RNE
  return (unsigned short)(x >> 16);
}
__device__ __forceinline__ float ldf(const void* p, long long i, bool bf){
  return bf ? bf2f(((const unsigned short*)p)[i]) : ((const float*)p)[i];
}
__device__ __forceinline__ void stf(void* p, size_t i, float v, bool bf){
  if (bf) ((unsigned short*)p)[i] = f2bf(v);
  else    ((float*)p)[i] = v;
}
__device__ __forceinline__ float bflo(unsigned int q){
  union { unsigned int i; float f; } v; v.i = q << 16; return v.f;
}
__device__ __forceinline__ float bfhi(unsigned int q){
  union { unsigned int i; float f; } v; v.i = q & 0xffff0000u; return v.f;
}
__device__ __forceinline__ void ld8(const unsigned short* p, float* o){
  uint4 q = *(const uint4*)p;
  o[0]=bflo(q.x); o[1]=bfhi(q.x); o[2]=bflo(q.y); o[3]=bfhi(q.y);
  o[4]=bflo(q.z); o[5]=bfhi(q.z); o[6]=bflo(q.w); o[7]=bfhi(q.w);
}
__device__ __forceinline__ void ld8g(const void* p, size_t i, bool bf, float* o){
  if (bf){ ld8((const unsigned short*)p + i, o); }
  else {
    const float4* q = (const float4*)((const float*)p + i);
    float4 x = q[0], y = q[1];
    o[0]=x.x; o[1]=x.y; o[2]=x.z; o[3]=x.w;
    o[4]=y.x; o[5]=y.y; o[6]=y.z; o[7]=y.w;
  }
}
__device__ __forceinline__ void st8(unsigned short* p, const float* v){
  uint4 q;
  q.x = (unsigned int)f2bf(v[0]) | ((unsigned int)f2bf(v[1]) << 16);
  q.y = (unsigned int)f2bf(v[2]) | ((unsigned int)f2bf(v[3]) << 16);
  q.z = (unsigned int)f2bf(v[4]) | ((unsigned int)f2bf(v[5]) << 16);
  q.w = (unsigned int)f2bf(v[6]) | ((unsigned int)f2bf(v[7]) << 16);
  *(uint4*)p = q;
}
// dot of a 200-long input row with f32 LDS x[200]
__device__ __forceinline__ float dotF(const void* wp, size_t off, const float* x, bool bf){
  float a0=0.f,a1=0.f,a2=0.f,a3=0.f;
  if (bf){
    const uint4* p = (const uint4*)((const unsigned short*)wp + off);
#pragma unroll
    for (int c = 0; c < FDIM/8; ++c){
      uint4 q = p[c];
      const float* xb = x + c*8;
      a0 += bflo(q.x)*xb[0]; a1 += bfhi(q.x)*xb[1];
      a2 += bflo(q.y)*xb[2]; a3 += bfhi(q.y)*xb[3];
      a0 += bflo(q.z)*xb[4]; a1 += bfhi(q.z)*xb[5];
      a2 += bflo(q.w)*xb[6]; a3 += bfhi(q.w)*xb[7];
    }
  } else {
    const float4* p = (const float4*)((const float*)wp + off);
#pragma unroll
    for (int c = 0; c < FDIM/4; ++c){
      float4 q = p[c];
      const float* xb = x + c*4;
      a0 += q.x*xb[0]; a1 += q.y*xb[1]; a2 += q.z*xb[2]; a3 += q.w*xb[3];
    }
  }
  return (a0+a1)+(a2+a3);
}
__device__ __forceinline__ float sigm(float x){ return 1.f/(1.f+__expf(-x)); }
__device__ __forceinline__ float tanh_(float x){
  float cx = fminf(fmaxf(x, -15.f), 15.f);
  float e = __expf(2.f*cx);
  return (e - 1.f)/(e + 1.f);
}
__device__ __forceinline__ float elu_(float x){ return x > 0.f ? x : __expf(x) - 1.f; }

// ---------- dtype probe: atom_mask is all 1.0 ----------
__global__ void k_probe(const unsigned int* __restrict__ amask, int* __restrict__ mode){
  if (blockIdx.x == 0 && threadIdx.x == 0)
    *mode = (amask[0] == 0x3F803F80u) ? 1 : 0;
}

// ---------- weight repack -> chunk-major bf16 panels: chunk idx = base + c*Ng + n ----------
__global__ __launch_bounds__(256) void k_repack(unsigned short* __restrict__ wrep,
    const void* maw, const void* mwih, const void* mwhh,
    const void* alw, const void* atw, const void* gwih, const void* gwhh,
    const void* afw, const void* bfw, const int* __restrict__ mode){
  const bool bf = (*mode != 0);
  int idx = blockIdx.x*256 + threadIdx.x;
  if (idx >= WCHUNKS) return;
  int pb, Ng, kind; long long d = 0;     // kind: 0 ctx, 1 pair-mol, 2 spq, 3 pair-attn, 4 dec
  if (idx < PMG)      { pb = P1C; Ng = 256;  kind = 0; }
  else if (idx < PA0) { pb = PMG; Ng = 1536; kind = 1; }
  else if (idx < PG0) { pb = PA0; Ng = 640;  kind = 2; d = 0; }
  else if (idx < PA1) { pb = PG0; Ng = 1536; kind = 3; d = 0; }
  else if (idx < PG1) { pb = PA1; Ng = 640;  kind = 2; d = 1; }
  else if (idx < PD)  { pb = PG1; Ng = 1536; kind = 3; d = 1; }
  else                { pb = PD;  Ng = 128;  kind = 4; }
  int li = idx - pb;
  int c = li / Ng, n = li - c*Ng;
  const void* S = nullptr; long long sb = 0; int rl = 0, off = 0, row = 0;
  if (kind == 0){ if (n < 200){ S = maw; rl = 400; off = 200; row = n; } }
  else if (kind == 1 || kind == 3){
    int slot = n >> 8, f = n & 255;
    if (f < 200){
      int gate = (slot < 3) ? slot : slot - 3;
      if (kind == 1) S = (slot < 3) ? mwih : mwhh;
      else         { S = (slot < 3) ? gwih : gwhh; sb = d*120000; }
      rl = 200; row = gate*200 + f;
    }
  }
  else if (kind == 2){
    if (n < 200)      { S = alw; sb = d*80000; rl = 400; off = 0;   row = n; }
    else if (n < 400) { S = alw; sb = d*80000; rl = 400; off = 200; row = n-200; }
    else if (n < 600) { S = atw; sb = d*40000; rl = 200; off = 0;   row = n-400; }
  } else {
    if (n < 39)                { S = afw; rl = 200; row = n; }
    else if (n >= 40 && n < 50){ S = bfw; rl = 400; off = 0;   row = n-40; }
    else if (n >= 50 && n < 60){ S = bfw; rl = 400; off = 200; row = n-50; }
  }
  float v[8];
#pragma unroll
  for (int j = 0; j < 8; j++){
    int k = c*8 + j;
    v[j] = (S && k < 200) ? ldf(S, sb + (long long)row*rl + off + k, bf) : 0.f;
  }
  st8(wrep + (size_t)idx*8, v);
}

// ---------- bias-column table (f32) — layout unchanged ----------
__global__ __launch_bounds__(256) void k_biases(float* __restrict__ bt,
    const void* mbhh, const void* mbih, const void* alb, const void* atb,
    const void* gbhh, const void* gbih, const void* afb, const void* bfb,
    const int* __restrict__ mode){
  const bool bf = (*mode != 0);
  int e = blockIdx.x*256 + threadIdx.x;
  if (e >= NBIAS) return;
  float v = 0.f;
  if (e < 600)        v = ldf(mbhh, e, bf);
  else if (e < 1200)  v = ldf(mbih, e-600, bf);
  else if (e < 4800){
    int q = e - 1200; int d = q / 1800; q -= d*1800;
    if (q < 1200){
      if (q < 200)      v = ldf(alb, (long long)d*200 + q, bf);
      else if (q < 400) v = 0.f;
      else if (q < 600) v = ldf(atb, (long long)d*200 + q-400, bf);
      else              v = ldf(gbhh, (long long)d*600 + q-600, bf);
    } else              v = ldf(gbih, (long long)d*600 + q-1200, bf);
  } else {
    int q = e - 4800;
    if (q < 39)                 v = ldf(afb, q, bf);
    else if (q >= 40 && q < 50) v = ldf(bfb, q-40, bf);
  }
  bt[e] = v;
}

// ---------- GEMM: W-in-LDS 128x64 tile + XCD swizzle + LDS-transpose epilogue ----------
// emode: 0 plain | 1 acc+=bias[col] | 2 elu(pre_row[col]+acc)
__global__ __launch_bounds__(256, 5) void k_gemm(
    const unsigned short* __restrict__ A,
    const unsigned short* __restrict__ Wc, int wNg, int npan,
    unsigned short* __restrict__ C, int ldc, int Nout,
    int emode, const float* __restrict__ bias, int gbase)
{
  __shared__ unsigned short Ws[KCH*64*8];     // 28,672 B -> 5 blocks/CU
  int t = threadIdx.x;
  int bid = blockIdx.x;
  int res = bid & 7, q = bid >> 3;
  int p = q % npan;
  int mt = (q / npan)*8 + res;
  int nbase = p * 64;
  int mbase = mt * 128;
  const uint4* Wg = (const uint4*)Wc;
  uint4* Wl = (uint4*)Ws;
  for (int i = t; i < KCH*64; i += 256){      // linear LDS write: conflict-free
    int c = i >> 6, n = i & 63;
    Wl[i] = Wg[(size_t)c*wNg + nbase + n];
  }
  __syncthreads();
  int wave = t >> 6, lane = t & 63;
  int quad = lane >> 4, l16 = lane & 15;
  const unsigned short* A0 = A + (size_t)(mbase + wave*32 + l16)*FDIM + quad*8;
  v4f acc[2][4];
#pragma unroll
  for (int ms = 0; ms < 2; ms++)
#pragma unroll
    for (int ns = 0; ns < 4; ns++) acc[ms][ns] = (v4f){0.f,0.f,0.f,0.f};
#pragma unroll
  for (int ks = 0; ks < 7; ks++){
    v8s a0 = *(const v8s*)(A0 + ks*32);              // k>=200 garbage x zero-W = 0
    v8s a1 = *(const v8s*)(A0 + 16*FDIM + ks*32);
    const unsigned short* Bp = Ws + ((ks*4 + quad)*64 + l16)*8;
#pragma unroll
    for (int ns = 0; ns < 4; ns++){
      v8s b = *(const v8s*)(Bp + ns*128);            // 16 lanes consecutive 16B: conflict-free
      acc[0][ns] = __builtin_amdgcn_mfma_f32_16x16x32_bf16(a0, b, acc[0][ns], 0, 0, 0);
      acc[1][ns] = __builtin_amdgcn_mfma_f32_16x16x32_bf16(a1, b, acc[1][ns], 0, 0, 0);
    }
  }
  // ---- LDS-transpose epilogue: acc -> Ws (stride 72) -> 16B coalesced stores ----
  __syncthreads();                            // all waves done reading W tile
  const float* pr = (emode == 2) ? (bias + (size_t)(((gbase + mbase) >> 8))*FDIM) : nullptr;
#pragma unroll
  for (int ms = 0; ms < 2; ms++){
#pragma unroll
    for (int ns = 0; ns < 4; ns++){
      int lcol = l16 + ns*16;                 // 0..63
      int col = nbase + lcol;
      float badd = (emode == 1 && col < Nout) ? bias[col] : 0.f;
      float pv   = (emode == 2) ? pr[col] : 0.f;
      int lrow = wave*32 + ms*16 + quad*4;    // + reg
#pragma unroll
      for (int reg = 0; reg < 4; reg++){
        float v = acc[ms][ns][reg] + badd;
        if (emode == 2) v = elu_(pv + v);
        Ws[(lrow + reg)*72 + lcol] = f2bf(v);
      }
    }
  }
  __syncthreads();
#pragma unroll
  for (int j = 0; j < 4; j++){
    int g = t + j*256;                        // 0..1023: 128 rows x 8 col-groups
    int row = g >> 3, cg = g & 7;
    int col = nbase + cg*8;
    if (col < Nout){                          // Nout % 8 == 0 for all shapes
      uint4 qv = *(const uint4*)(Ws + row*72 + cg*8);
      *(uint4*)(C + (size_t)(mbase + row)*ldc + col) = qv;
    }
  }
}

// ---------- FULLY-FUSED GRU, phase-split, 5-wave VGPR budget (no spills) ----------
// Phase 1: stage gi slots (0..2), MFMA vs ctx. Phase 2: re-stage gh slots (3..5),
// MFMA vs act. LDS 21,504 B; VGPR ~68 -> HW can still run up to 7 blocks/CU.
__global__ __launch_bounds__(256, 5) void k_gru2(
    const unsigned short* __restrict__ ctxA,
    const unsigned short* __restrict__ actS,
    unsigned short* __restrict__ actD,
    const unsigned short* __restrict__ Wc,
    const float* __restrict__ gib, const float* __restrict__ ghb,
    int dorelu)
{
  __shared__ unsigned short Ws[3*KCH*16*8];   // 21,504 B
  int t = threadIdx.x, bid = blockIdx.x;
  int res = bid & 7, q = bid >> 3;
  int p = q % 13;
  int mt = (q / 13)*8 + res;
  int f0 = p*16;
  int mbase = mt*128;
  const uint4* Wg = (const uint4*)Wc;
  uint4* Wl = (uint4*)Ws;
  int wave = t >> 6, lane = t & 63;
  int quad = lane >> 4, l16 = lane & 15;
  v4f acc[6][2];
#pragma unroll
  for (int s = 0; s < 6; s++)
#pragma unroll
    for (int ms = 0; ms < 2; ms++) acc[s][ms] = (v4f){0.f,0.f,0.f,0.f};

#pragma unroll
  for (int ph = 0; ph < 2; ph++){
    // stage 3 slots of this phase
    if (ph) __syncthreads();                  // all waves done reading phase-0 Ws
    for (int i = t; i < 3*KCH*16; i += 256){
      int s = i / (KCH*16), r2 = i - s*(KCH*16);
      int c = r2 >> 4, n = r2 & 15;
      Wl[i] = Wg[(size_t)c*1536 + (ph*3 + s)*256 + f0 + n];
    }
    __syncthreads();
    const unsigned short* Ax = (ph == 0 ? ctxA : actS)
                             + (size_t)(mbase + wave*32 + l16)*FDIM + quad*8;
#pragma unroll
    for (int ks = 0; ks < 7; ks++){
      v8s x0 = *(const v8s*)(Ax + ks*32);
      v8s x1 = *(const v8s*)(Ax + 16*FDIM + ks*32);
#pragma unroll
      for (int s = 0; s < 3; s++){
        v8s b = *(const v8s*)(Ws + ((size_t)(s*KCH + ks*4 + quad)*16 + l16)*8);
        acc[ph*3+s][0] = __builtin_amdgcn_mfma_f32_16x16x32_bf16(x0, b, acc[ph*3+s][0], 0, 0, 0);
        acc[ph*3+s][1] = __builtin_amdgcn_mfma_f32_16x16x32_bf16(x1, b, acc[ph*3+s][1], 0, 0, 0);
      }
    }
  }
  int f = f0 + l16;
  if (f < 200){
    float bir = gib[f], biz = gib[200+f], bin = gib[400+f];
    float bhr = ghb[f], bhz = ghb[200+f], bhn = ghb[400+f];
#pragma unroll
    for (int ms = 0; ms < 2; ms++){
#pragma unroll
      for (int reg = 0; reg < 4; reg++){
        int row = mbase + wave*32 + ms*16 + quad*4 + reg;
        float h = bf2f(actS[(size_t)row*FDIM + f]);
        float r = sigm(acc[0][ms][reg] + bir + acc[3][ms][reg] + bhr);
        float z = sigm(acc[1][ms][reg] + biz + acc[4][ms][reg] + bhz);
        float n = tanh_(acc[2][ms][reg] + bin + r*(acc[5][ms][reg] + bhn));
        float hn = (1.f - z)*n + z*h;
        if (dorelu) hn = fmaxf(hn, 0.f);
        actD[(size_t)row*FDIM + f] = f2bf(hn);
      }
    }
  }
}

// ---------- pre_mol[b,f] = mab[f] + dot(mol[b], maw[f, :F]) ----------
__global__ __launch_bounds__(256) void k_premol(float* __restrict__ pre,
    const void* __restrict__ molf, const void* __restrict__ maw,
    const void* __restrict__ mab, const int* __restrict__ mode){
  const bool bf = (*mode != 0);
  int b = blockIdx.x, t = threadIdx.x;
  __shared__ float mf[FDIM];
  for (int f = t; f < FDIM; f += 256) mf[f] = ldf(molf, (size_t)b*FDIM+f, bf);
  __syncthreads();
  for (int f = t; f < FDIM; f += 256)
    pre[b*FDIM+f] = ldf(mab, f, bf) + dotF(maw, (size_t)f*2*FDIM, mf, bf);
}

// ---------- mw[b,l] = softmax_l(dot(act[b,l], mol[b])) ----------
__global__ __launch_bounds__(LL) void k_gitdot(float* __restrict__ mw_out,
    const void* __restrict__ molf, const void* __restrict__ actf,
    const int* __restrict__ mode){
  const bool bf = (*mode != 0);
  int b = blockIdx.x, l = threadIdx.x;
  __shared__ float mf[FDIM];
  __shared__ float red[LL];
  for (int f = l; f < FDIM; f += LL) mf[f] = ldf(molf, (size_t)b*FDIM+f, bf);
  __syncthreads();
  float d = dotF(actf, ((size_t)b*LL + l)*FDIM, mf, bf);
  red[l] = d; __syncthreads();
  for (int s = 128; s > 0; s >>= 1){ if (l < s) red[l] = fmaxf(red[l], red[l+s]); __syncthreads(); }
  float m = red[0]; __syncthreads();
  float e = __expf(d - m);
  red[l] = e; __syncthreads();
  for (int s = 128; s > 0; s >>= 1){ if (l < s) red[l] += red[l+s]; __syncthreads(); }
  mw_out[(size_t)b*LL + l] = e / red[0];
}

// ---------- act[row,f] = mw[row]*mol[b,f] + actf[row,f] ----------
__global__ __launch_bounds__(256) void k_gitwrite(unsigned short* __restrict__ act,
    const void* __restrict__ molf, const void* __restrict__ actf,
    const float* __restrict__ mw, const int* __restrict__ mode){
  const bool bf = (*mode != 0);
  int idx = blockIdx.x*256 + threadIdx.x;
  if (idx >= BL*25) return;
  int row = idx/25, f0 = (idx - row*25)*8;
  int b = row >> 8;
  float m = mw[row];
  float mv[8], av[8], v[8];
  ld8g(molf, (size_t)b*FDIM + f0, bf, mv);
  ld8g(actf, (size_t)row*FDIM + f0, bf, av);
#pragma unroll
  for (int j = 0; j < 8; j++) v[j] = m*mv[j] + av[j];
  st8(act + (size_t)row*FDIM + f0, v);
}

// ---------- attention elementwise, 8-wide: big[S'|P|Q'] stride 600 -> ctx ----------
__global__ __launch_bounds__(256) void k_attn_ew(const unsigned short* __restrict__ big,
    unsigned short* __restrict__ ctx, const int* __restrict__ adeg,
    int base, int total){
  int idx = blockIdx.x*256 + threadIdx.x;
  if (idx >= total) return;
  int a = idx/25, f0 = (idx - a*25)*8;
  int mb = (a >> 8) << 8;
  float s0[8];
  ld8(big + (size_t)a*600 + f0, s0);
  int4 d0 = *(const int4*)(adeg + (size_t)(base + a)*NN);
  int4 d1 = *(const int4*)(adeg + (size_t)(base + a)*NN + 4);
  int iv[NN] = {d0.x, d0.y, d0.z, d0.w, d1.x, d1.y, d1.z, d1.w};
  int nid[NN]; float nmul[NN], nadd[NN];
#pragma unroll
  for (int n = 0; n < NN; n++){
    nid[n] = mb + iv[n];
    bool pad = (iv[n] == LL-1);
    nmul[n] = pad ? 0.f : 1.f;
    nadd[n] = pad ? -9e8f : 0.f;
  }
  float e[NN][8], mx[8];
#pragma unroll
  for (int j = 0; j < 8; j++) mx[j] = -1e30f;
#pragma unroll
  for (int n = 0; n < NN; n++){
    float p[8];
    ld8(big + (size_t)nid[n]*600 + 200 + f0, p);
#pragma unroll
    for (int j = 0; j < 8; j++){
      float s = s0[j] + p[j];
      s = s > 0.f ? s : 0.01f*s;
      s += nadd[n];
      e[n][j] = s;
      mx[j] = fmaxf(mx[j], s);
    }
  }
  float sum[8] = {0,0,0,0,0,0,0,0};
#pragma unroll
  for (int n = 0; n < NN; n++)
#pragma unroll
    for (int j = 0; j < 8; j++){ e[n][j] = __expf(e[n][j] - mx[j]); sum[j] += e[n][j]; }
  float acc[8] = {0,0,0,0,0,0,0,0};
#pragma unroll
  for (int n = 0; n < NN; n++){
    float q[8];
    ld8(big + (size_t)nid[n]*600 + 400 + f0, q);
#pragma unroll
    for (int j = 0; j < 8; j++) acc[j] += e[n][j]*nmul[n]*q[j];
  }
  float o[8];
#pragma unroll
  for (int j = 0; j < 8; j++) o[j] = elu_(acc[j]/sum[j]);
  st8(ctx + (size_t)a*FDIM + f0, o);
}

// ---------- merged decode: 4 atoms/block (biases pre-folded into big) ----------
__global__ __launch_bounds__(256) void k_dec(const unsigned short* __restrict__ big,
    const int* __restrict__ adeg, void* __restrict__ out, int base,
    const int* __restrict__ mode){
  const bool bf = (*mode != 0);
  const size_t obase = (size_t)BL*AOUTD;
  int sub = threadIdx.x >> 6, tl = threadIdx.x & 63;
  int a = blockIdx.x*4 + sub;
  __shared__ float al[4][40];
  __shared__ float sm[4][4], ss[4][4];
  const int lo[4] = {0,16,24,31}, hi[4] = {16,22,30,36};
  if (tl < AOUTD) al[sub][tl] = bf2f(big[(size_t)a*64 + tl]);
  __syncthreads();
  if (tl < 4){
    float m = -1e30f;
    for (int k = lo[tl]; k < hi[tl]; k++) m = fmaxf(m, al[sub][k]);
    float s = 0.f;
    for (int k = lo[tl]; k < hi[tl]; k++) s += __expf(al[sub][k]-m);
    sm[sub][tl] = m; ss[sub][tl] = s;
  }
  __syncthreads();
  if (tl < AOUTD){
    float v = 0.f;
#pragma unroll
    for (int g = 0; g < 4; g++)
      if (tl >= lo[g] && tl < hi[g]) v += __expf(al[sub][tl]-sm[sub][g])/ss[sub][g];
    if (tl == 24) v += fmaxf(al[sub][24], 0.f);
    if (tl == 30 || tl == 36 || tl == 37 || tl == 38) v += sigm(al[sub][tl]);
    stf(out, (size_t)(base + a)*AOUTD + tl, v, bf);
  } else if (tl >= 40 && tl < 48){
    int n = tl - 40;
    int iv = adeg[((size_t)(base + a))*NN + n];
    int vr = ((a >> 8) << 8) + iv;
    float bl[BOUTD];
#pragma unroll
    for (int o = 0; o < BOUTD; o++)
      bl[o] = bf2f(big[(size_t)a*64 + 40 + o]) + bf2f(big[(size_t)vr*64 + 50 + o]);
    float v[BOUTD];
    float m0 = fmaxf(fmaxf(bl[0],bl[1]), fmaxf(bl[2],bl[3]));
    float e0[4], s0 = 0.f;
#pragma unroll
    for (int j = 0; j < 4; j++){ e0[j] = __expf(bl[j]-m0); s0 += e0[j]; }
    float m1 = fmaxf(fmaxf(bl[6],bl[7]), fmaxf(bl[8],bl[9]));
    float e1[4], s1 = 0.f;
#pragma unroll
    for (int j = 0; j < 4; j++){ e1[j] = __expf(bl[6+j]-m1); s1 += e1[j]; }
#pragma unroll
    for (int j = 0; j < 4; j++) v[j] = e0[j]/s0;
    v[4] = sigm(bl[4]); v[5] = sigm(bl[5]);
#pragma unroll
    for (int j = 0; j < 4; j++) v[6+j] = e1[j]/s1;
    size_t op = obase + ((size_t)(base + a)*NN + n)*BOUTD;
#pragma unroll
    for (int j = 0; j < BOUTD; j++) stf(out, op + j, v[j], bf);
  }
}

extern "C" void kernel_launch(void* const* d_in, const int* in_sizes, int n_in,
                              void* d_out, int out_size, void* d_ws, size_t ws_size,
                              hipStream_t stream) {
  const int* adeg = (const int*)d_in[2];
  const void* amask = d_in[4];
  const void* molf = d_in[5];
  const void* actf = d_in[6];
  const void* afw = d_in[7];  const void* afb = d_in[8];
  const void* bfw = d_in[9];  const void* bfb = d_in[10];
  const void* alw = d_in[11]; const void* alb = d_in[12];
  const void* atw = d_in[13]; const void* atb = d_in[14];
  const void* gwih = d_in[15]; const void* gwhh = d_in[16];
  const void* gbih = d_in[17]; const void* gbhh = d_in[18];
  const void* maw = d_in[19]; const void* mab = d_in[20];
  const void* mwih = d_in[21]; const void* mwhh = d_in[22];
  const void* mbih = d_in[23]; const void* mbhh = d_in[24];

  // ---- ws layout: act0 | act1 | mw | pre | wrep | bt | mode | ctx[CH] | big[CH,600] ----
  char* w = (char*)d_ws;
  unsigned short* act0 = (unsigned short*)w;  w += (size_t)BL*FDIM*2;           // 13.11 MB
  unsigned short* act1 = (unsigned short*)w;  w += (size_t)BL*FDIM*2;           // 13.11 MB
  float*          mw   = (float*)w;           w += (size_t)BL*4;
  float*          pre  = (float*)w;           w += (size_t)BB*FDIM*4;
  unsigned short* wrep = (unsigned short*)w;  w += (size_t)WCHUNKS*16;          // 2.81 MB
  float*          bt   = (float*)w;           w += (size_t)NBIAS*4;
  int*            mode = (int*)w;             w += 16;
  size_t fixed = (size_t)(w - (char*)d_ws);
  int CH = 8192;
  if (ws_size >= fixed + (size_t)32768*1600) CH = 32768;
  else if (ws_size >= fixed + (size_t)16384*1600) CH = 16384;
  unsigned short* ctx = (unsigned short*)w;   w += (size_t)CH*FDIM*2;
  unsigned short* big = (unsigned short*)w;                                     // [CH][600]
  const int NCH = BL / CH;
  const int EWT = CH*25, EWB = EWT/256;
  const int GY = CH/128;           // row-tiles per chunk (divisible by 8)

  k_probe<<<1, 64, 0, stream>>>((const unsigned int*)amask, mode);
  k_repack<<<(WCHUNKS + 255)/256, 256, 0, stream>>>(wrep, maw, mwih, mwhh,
      alw, atw, gwih, gwhh, afw, bfw, mode);
  k_biases<<<(NBIAS + 255)/256, 256, 0, stream>>>(bt, mbhh, mbih, alb, atb,
      gbhh, gbih, afb, bfb, mode);
  k_premol<<<BB, 256, 0, stream>>>(pre, molf, maw, mab, mode);
  k_gitdot<<<BB, LL, 0, stream>>>(mw, molf, actf, mode);
  k_gitwrite<<<(BL*25 + 255)/256, 256, 0, stream>>>(act0, molf, actf, mw, mode);

  unsigned short* cur = act0;
  unsigned short* alt = act1;

  // ---- mol GRU x2: ctx GEMM -> fully-fused GRU (gi+gh+update) ----
  for (int ts = 0; ts < 2; ts++){
    for (int c = 0; c < NCH; c++){
      int base = c*CH;
      unsigned short* Ac = cur + (size_t)base*FDIM;
      k_gemm<<<4*GY, 256, 0, stream>>>(Ac, wrep + (size_t)P1C*8, 256, 4,
          ctx, FDIM, FDIM, 2, pre, base);                                       // ctx = elu(pre+.)
      k_gru2<<<13*GY, 256, 0, stream>>>(ctx, Ac, alt + (size_t)base*FDIM,
          wrep + (size_t)PMG*8, bt + 600, bt + 0, (ts==1));
    }
    { unsigned short* tmp = cur; cur = alt; alt = tmp; }
  }
  // ---- 2 attention+GRU rounds ----
  for (int d = 0; d < 2; d++){
    size_t pA = (d ? PA1 : PA0), pG = (d ? PG1 : PG0);
    float* btA = bt + 1200 + d*1800;          // alb|0|atb (600 entries)
    float* gib = bt + 2400 + d*1800;          // gbih
    float* ghb = bt + 1800 + d*1800;          // gbhh
    for (int c = 0; c < NCH; c++){
      int base = c*CH;
      unsigned short* Ac = cur + (size_t)base*FDIM;
      k_gemm<<<10*GY, 256, 0, stream>>>(Ac, wrep + pA*8, 640, 10,
          big, 600, 600, 1, btA, 0);                                            // S'|P|Q'
      k_attn_ew<<<EWB, 256, 0, stream>>>(big, ctx, adeg, base, EWT);
      k_gru2<<<13*GY, 256, 0, stream>>>(ctx, Ac, alt + (size_t)base*FDIM,
          wrep + pG*8, gib, ghb, 1);
    }
    { unsigned short* tmp = cur; cur = alt; alt = tmp; }
  }
  // ---- decode (cur == act0 after 4 swaps) ----
  for (int c = 0; c < NCH; c++){
    int base = c*CH;
    unsigned short* Ac = cur + (size_t)base*FDIM;
    k_gemm<<<1*GY, 256, 0, stream>>>(Ac, wrep + (size_t)PD*8, 128, 1,
        big, 64, 64, 1, bt + 4800, 0);                                          // AL|U|V (+afb,bfb)
    k_dec<<<CH/4, 256, 0, stream>>>(big, adeg, d_out, base, mode);
  }
}

// Round 21
// 505.222 us; speedup vs baseline: 1.0971x; 1.0217x over previous
//
#include <hip/hip_runtime.h>
#include <hip/hip_bf16.h>

#define FDIM 200
#define BB   128
#define LL   256
#define NN   8
#define BL   (BB*LL)
#define AOUTD 39
#define BOUTD 10
#define KCH  28            // K chunks of 8 elems (224 = 7 MFMA steps x 32)

// chunk-major weight panels (16B chunk index bases)
#define P1C 0              // mol ctx (maw_n)  Ng=256        -> 7168
#define PMG 7168           // mol gi|gh pair   Ng=1536       -> 50176
#define PA0 50176          // rd0 S|P|Q        Ng=640        -> 68096
#define PG0 68096          // rd0 pair         Ng=1536       -> 111104
#define PA1 111104         // rd1 S|P|Q        Ng=640        -> 129024
#define PG1 129024         // rd1 pair         Ng=1536       -> 172032
#define PD  172032         // dec AL|U|V       Ng=128        -> 175616
#define WCHUNKS 175616
#define NBIAS 4864         // f32 bias-column table entries

typedef short v8s __attribute__((ext_vector_type(8)));
typedef float v4f __attribute__((ext_vector_type(4)));

// ---------- dtype helpers (runtime bf16-vs-f32 mode for INPUT tensors) ----------
__device__ __forceinline__ float bf2f(unsigned short u){
  union { unsigned int i; float f; } v; v.i = ((unsigned int)u) << 16; return v.f;
}
__device__ __forceinline__ unsigned short f2bf(float f){
  unsigned int x = __float_as_uint(f);
  x += 0x7fffu + ((x >> 16) & 1u);   // RNE
  return (unsigned short)(x >> 16);
}
__device__ __forceinline__ float ldf(const void* p, long long i, bool bf){
  return bf ? bf2f(((const unsigned short*)p)[i]) : ((const float*)p)[i];
}
__device__ __forceinline__ void stf(void* p, size_t i, float v, bool bf){
  if (bf) ((unsigned short*)p)[i] = f2bf(v);
  else    ((float*)p)[i] = v;
}
__device__ __forceinline__ float bflo(unsigned int q){
  union { unsigned int i; float f; } v; v.i = q << 16; return v.f;
}
__device__ __forceinline__ float bfhi(unsigned int q){
  union { unsigned int i; float f; } v; v.i = q & 0xffff0000u; return v.f;
}
__device__ __forceinline__ void ld8(const unsigned short* p, float* o){
  uint4 q = *(const uint4*)p;
  o[0]=bflo(q.x); o[1]=bfhi(q.x); o[2]=bflo(q.y); o[3]=bfhi(q.y);
  o[4]=bflo(q.z); o[5]=bfhi(q.z); o[6]=bflo(q.w); o[7]=bfhi(q.w);
}
__device__ __forceinline__ void ld8g(const void* p, size_t i, bool bf, float* o){
  if (bf){ ld8((const unsigned short*)p + i, o); }
  else {
    const float4* q = (const float4*)((const float*)p + i);
    float4 x = q[0], y = q[1];
    o[0]=x.x; o[1]=x.y; o[2]=x.z; o[3]=x.w;
    o[4]=y.x; o[5]=y.y; o[6]=y.z; o[7]=y.w;
  }
}
__device__ __forceinline__ void st8(unsigned short* p, const float* v){
  uint4 q;
  q.x = (unsigned int)f2bf(v[0]) | ((unsigned int)f2bf(v[1]) << 16);
  q.y = (unsigned int)f2bf(v[2]) | ((unsigned int)f2bf(v[3]) << 16);
  q.z = (unsigned int)f2bf(v[4]) | ((unsigned int)f2bf(v[5]) << 16);
  q.w = (unsigned int)f2bf(v[6]) | ((unsigned int)f2bf(v[7]) << 16);
  *(uint4*)p = q;
}
// dot of a 200-long input row with f32 LDS x[200]
__device__ __forceinline__ float dotF(const void* wp, size_t off, const float* x, bool bf){
  float a0=0.f,a1=0.f,a2=0.f,a3=0.f;
  if (bf){
    const uint4* p = (const uint4*)((const unsigned short*)wp + off);
#pragma unroll
    for (int c = 0; c < FDIM/8; ++c){
      uint4 q = p[c];
      const float* xb = x + c*8;
      a0 += bflo(q.x)*xb[0]; a1 += bfhi(q.x)*xb[1];
      a2 += bflo(q.y)*xb[2]; a3 += bfhi(q.y)*xb[3];
      a0 += bflo(q.z)*xb[4]; a1 += bfhi(q.z)*xb[5];
      a2 += bflo(q.w)*xb[6]; a3 += bfhi(q.w)*xb[7];
    }
  } else {
    const float4* p = (const float4*)((const float*)wp + off);
#pragma unroll
    for (int c = 0; c < FDIM/4; ++c){
      float4 q = p[c];
      const float* xb = x + c*4;
      a0 += q.x*xb[0]; a1 += q.y*xb[1]; a2 += q.z*xb[2]; a3 += q.w*xb[3];
    }
  }
  return (a0+a1)+(a2+a3);
}
__device__ __forceinline__ float sigm(float x){ return 1.f/(1.f+__expf(-x)); }
__device__ __forceinline__ float tanh_(float x){
  float cx = fminf(fmaxf(x, -15.f), 15.f);
  float e = __expf(2.f*cx);
  return (e - 1.f)/(e + 1.f);
}
__device__ __forceinline__ float elu_(float x){ return x > 0.f ? x : __expf(x) - 1.f; }

// ---------- dtype probe: atom_mask is all 1.0 ----------
__global__ void k_probe(const unsigned int* __restrict__ amask, int* __restrict__ mode){
  if (blockIdx.x == 0 && threadIdx.x == 0)
    *mode = (amask[0] == 0x3F803F80u) ? 1 : 0;
}

// ---------- weight repack -> chunk-major bf16 panels: chunk idx = base + c*Ng + n ----------
__global__ __launch_bounds__(256) void k_repack(unsigned short* __restrict__ wrep,
    const void* maw, const void* mwih, const void* mwhh,
    const void* alw, const void* atw, const void* gwih, const void* gwhh,
    const void* afw, const void* bfw, const int* __restrict__ mode){
  const bool bf = (*mode != 0);
  int idx = blockIdx.x*256 + threadIdx.x;
  if (idx >= WCHUNKS) return;
  int pb, Ng, kind; long long d = 0;     // kind: 0 ctx, 1 pair-mol, 2 spq, 3 pair-attn, 4 dec
  if (idx < PMG)      { pb = P1C; Ng = 256;  kind = 0; }
  else if (idx < PA0) { pb = PMG; Ng = 1536; kind = 1; }
  else if (idx < PG0) { pb = PA0; Ng = 640;  kind = 2; d = 0; }
  else if (idx < PA1) { pb = PG0; Ng = 1536; kind = 3; d = 0; }
  else if (idx < PG1) { pb = PA1; Ng = 640;  kind = 2; d = 1; }
  else if (idx < PD)  { pb = PG1; Ng = 1536; kind = 3; d = 1; }
  else                { pb = PD;  Ng = 128;  kind = 4; }
  int li = idx - pb;
  int c = li / Ng, n = li - c*Ng;
  const void* S = nullptr; long long sb = 0; int rl = 0, off = 0, row = 0;
  if (kind == 0){ if (n < 200){ S = maw; rl = 400; off = 200; row = n; } }
  else if (kind == 1 || kind == 3){
    int slot = n >> 8, f = n & 255;
    if (f < 200){
      int gate = (slot < 3) ? slot : slot - 3;
      if (kind == 1) S = (slot < 3) ? mwih : mwhh;
      else         { S = (slot < 3) ? gwih : gwhh; sb = d*120000; }
      rl = 200; row = gate*200 + f;
    }
  }
  else if (kind == 2){
    if (n < 200)      { S = alw; sb = d*80000; rl = 400; off = 0;   row = n; }
    else if (n < 400) { S = alw; sb = d*80000; rl = 400; off = 200; row = n-200; }
    else if (n < 600) { S = atw; sb = d*40000; rl = 200; off = 0;   row = n-400; }
  } else {
    if (n < 39)                { S = afw; rl = 200; row = n; }
    else if (n >= 40 && n < 50){ S = bfw; rl = 400; off = 0;   row = n-40; }
    else if (n >= 50 && n < 60){ S = bfw; rl = 400; off = 200; row = n-50; }
  }
  float v[8];
#pragma unroll
  for (int j = 0; j < 8; j++){
    int k = c*8 + j;
    v[j] = (S && k < 200) ? ldf(S, sb + (long long)row*rl + off + k, bf) : 0.f;
  }
  st8(wrep + (size_t)idx*8, v);
}

// ---------- bias-column table (f32) — layout unchanged ----------
__global__ __launch_bounds__(256) void k_biases(float* __restrict__ bt,
    const void* mbhh, const void* mbih, const void* alb, const void* atb,
    const void* gbhh, const void* gbih, const void* afb, const void* bfb,
    const int* __restrict__ mode){
  const bool bf = (*mode != 0);
  int e = blockIdx.x*256 + threadIdx.x;
  if (e >= NBIAS) return;
  float v = 0.f;
  if (e < 600)        v = ldf(mbhh, e, bf);
  else if (e < 1200)  v = ldf(mbih, e-600, bf);
  else if (e < 4800){
    int q = e - 1200; int d = q / 1800; q -= d*1800;
    if (q < 1200){
      if (q < 200)      v = ldf(alb, (long long)d*200 + q, bf);
      else if (q < 400) v = 0.f;
      else if (q < 600) v = ldf(atb, (long long)d*200 + q-400, bf);
      else              v = ldf(gbhh, (long long)d*600 + q-600, bf);
    } else              v = ldf(gbih, (long long)d*600 + q-1200, bf);
  } else {
    int q = e - 4800;
    if (q < 39)                 v = ldf(afb, q, bf);
    else if (q >= 40 && q < 50) v = ldf(bfb, q-40, bf);
  }
  bt[e] = v;
}

// ---------- GEMM: W-in-LDS 128x64 tile + XCD swizzle + LDS-transpose epilogue ----------
// emode: 0 plain | 1 acc+=bias[col] | 2 elu(pre_row[col]+acc)
__global__ __launch_bounds__(256, 5) void k_gemm(
    const unsigned short* __restrict__ A,
    const unsigned short* __restrict__ Wc, int wNg, int npan,
    unsigned short* __restrict__ C, int ldc, int Nout,
    int emode, const float* __restrict__ bias, int gbase)
{
  __shared__ unsigned short Ws[KCH*64*8];     // 28,672 B -> 5 blocks/CU
  int t = threadIdx.x;
  int bid = blockIdx.x;
  int res = bid & 7, q = bid >> 3;
  int p = q % npan;
  int mt = (q / npan)*8 + res;
  int nbase = p * 64;
  int mbase = mt * 128;
  const uint4* Wg = (const uint4*)Wc;
  uint4* Wl = (uint4*)Ws;
  for (int i = t; i < KCH*64; i += 256){      // linear LDS write: conflict-free
    int c = i >> 6, n = i & 63;
    Wl[i] = Wg[(size_t)c*wNg + nbase + n];
  }
  __syncthreads();
  int wave = t >> 6, lane = t & 63;
  int quad = lane >> 4, l16 = lane & 15;
  const unsigned short* A0 = A + (size_t)(mbase + wave*32 + l16)*FDIM + quad*8;
  v4f acc[2][4];
#pragma unroll
  for (int ms = 0; ms < 2; ms++)
#pragma unroll
    for (int ns = 0; ns < 4; ns++) acc[ms][ns] = (v4f){0.f,0.f,0.f,0.f};
#pragma unroll
  for (int ks = 0; ks < 7; ks++){
    v8s a0 = *(const v8s*)(A0 + ks*32);              // k>=200 garbage x zero-W = 0
    v8s a1 = *(const v8s*)(A0 + 16*FDIM + ks*32);
    const unsigned short* Bp = Ws + ((ks*4 + quad)*64 + l16)*8;
#pragma unroll
    for (int ns = 0; ns < 4; ns++){
      v8s b = *(const v8s*)(Bp + ns*128);            // 16 lanes consecutive 16B: conflict-free
      acc[0][ns] = __builtin_amdgcn_mfma_f32_16x16x32_bf16(a0, b, acc[0][ns], 0, 0, 0);
      acc[1][ns] = __builtin_amdgcn_mfma_f32_16x16x32_bf16(a1, b, acc[1][ns], 0, 0, 0);
    }
  }
  // ---- LDS-transpose epilogue: acc -> Ws (stride 72) -> 16B coalesced stores ----
  __syncthreads();                            // all waves done reading W tile
  const float* pr = (emode == 2) ? (bias + (size_t)(((gbase + mbase) >> 8))*FDIM) : nullptr;
#pragma unroll
  for (int ms = 0; ms < 2; ms++){
#pragma unroll
    for (int ns = 0; ns < 4; ns++){
      int lcol = l16 + ns*16;                 // 0..63
      int col = nbase + lcol;
      float badd = (emode == 1 && col < Nout) ? bias[col] : 0.f;
      float pv   = (emode == 2) ? pr[col] : 0.f;
      int lrow = wave*32 + ms*16 + quad*4;    // + reg
#pragma unroll
      for (int reg = 0; reg < 4; reg++){
        float v = acc[ms][ns][reg] + badd;
        if (emode == 2) v = elu_(pv + v);
        Ws[(lrow + reg)*72 + lcol] = f2bf(v);
      }
    }
  }
  __syncthreads();
#pragma unroll
  for (int j = 0; j < 4; j++){
    int g = t + j*256;                        // 0..1023: 128 rows x 8 col-groups
    int row = g >> 3, cg = g & 7;
    int col = nbase + cg*8;
    if (col < Nout){                          // Nout % 8 == 0 for all shapes
      uint4 qv = *(const uint4*)(Ws + row*72 + cg*8);
      *(uint4*)(C + (size_t)(mbase + row)*ldc + col) = qv;
    }
  }
}

// ---------- FULLY-FUSED GRU, phase-split, 5-wave VGPR budget (no spills) ----------
__global__ __launch_bounds__(256, 5) void k_gru2(
    const unsigned short* __restrict__ ctxA,
    const unsigned short* __restrict__ actS,
    unsigned short* __restrict__ actD,
    const unsigned short* __restrict__ Wc,
    const float* __restrict__ gib, const float* __restrict__ ghb,
    int dorelu)
{
  __shared__ unsigned short Ws[3*KCH*16*8];   // 21,504 B
  int t = threadIdx.x, bid = blockIdx.x;
  int res = bid & 7, q = bid >> 3;
  int p = q % 13;
  int mt = (q / 13)*8 + res;
  int f0 = p*16;
  int mbase = mt*128;
  const uint4* Wg = (const uint4*)Wc;
  uint4* Wl = (uint4*)Ws;
  int wave = t >> 6, lane = t & 63;
  int quad = lane >> 4, l16 = lane & 15;
  v4f acc[6][2];
#pragma unroll
  for (int s = 0; s < 6; s++)
#pragma unroll
    for (int ms = 0; ms < 2; ms++) acc[s][ms] = (v4f){0.f,0.f,0.f,0.f};

#pragma unroll
  for (int ph = 0; ph < 2; ph++){
    if (ph) __syncthreads();                  // all waves done reading phase-0 Ws
    for (int i = t; i < 3*KCH*16; i += 256){
      int s = i / (KCH*16), r2 = i - s*(KCH*16);
      int c = r2 >> 4, n = r2 & 15;
      Wl[i] = Wg[(size_t)c*1536 + (ph*3 + s)*256 + f0 + n];
    }
    __syncthreads();
    const unsigned short* Ax = (ph == 0 ? ctxA : actS)
                             + (size_t)(mbase + wave*32 + l16)*FDIM + quad*8;
#pragma unroll
    for (int ks = 0; ks < 7; ks++){
      v8s x0 = *(const v8s*)(Ax + ks*32);
      v8s x1 = *(const v8s*)(Ax + 16*FDIM + ks*32);
#pragma unroll
      for (int s = 0; s < 3; s++){
        v8s b = *(const v8s*)(Ws + ((size_t)(s*KCH + ks*4 + quad)*16 + l16)*8);
        acc[ph*3+s][0] = __builtin_amdgcn_mfma_f32_16x16x32_bf16(x0, b, acc[ph*3+s][0], 0, 0, 0);
        acc[ph*3+s][1] = __builtin_amdgcn_mfma_f32_16x16x32_bf16(x1, b, acc[ph*3+s][1], 0, 0, 0);
      }
    }
  }
  int f = f0 + l16;
  if (f < 200){
    float bir = gib[f], biz = gib[200+f], bin = gib[400+f];
    float bhr = ghb[f], bhz = ghb[200+f], bhn = ghb[400+f];
#pragma unroll
    for (int ms = 0; ms < 2; ms++){
#pragma unroll
      for (int reg = 0; reg < 4; reg++){
        int row = mbase + wave*32 + ms*16 + quad*4 + reg;
        float h = bf2f(actS[(size_t)row*FDIM + f]);
        float r = sigm(acc[0][ms][reg] + bir + acc[3][ms][reg] + bhr);
        float z = sigm(acc[1][ms][reg] + biz + acc[4][ms][reg] + bhz);
        float n = tanh_(acc[2][ms][reg] + bin + r*(acc[5][ms][reg] + bhn));
        float hn = (1.f - z)*n + z*h;
        if (dorelu) hn = fmaxf(hn, 0.f);
        actD[(size_t)row*FDIM + f] = f2bf(hn);
      }
    }
  }
}

// ---------- pre_mol[b,f] = mab[f] + dot(mol[b], maw[f, :F]) ----------
__global__ __launch_bounds__(256) void k_premol(float* __restrict__ pre,
    const void* __restrict__ molf, const void* __restrict__ maw,
    const void* __restrict__ mab, const int* __restrict__ mode){
  const bool bf = (*mode != 0);
  int b = blockIdx.x, t = threadIdx.x;
  __shared__ float mf[FDIM];
  for (int f = t; f < FDIM; f += 256) mf[f] = ldf(molf, (size_t)b*FDIM+f, bf);
  __syncthreads();
  for (int f = t; f < FDIM; f += 256)
    pre[b*FDIM+f] = ldf(mab, f, bf) + dotF(maw, (size_t)f*2*FDIM, mf, bf);
}

// ---------- parallel dots: d[b,l] = dot(act[b,l], mol[b]); 8 threads/atom ----------
__global__ __launch_bounds__(256) void k_gitdot2(float* __restrict__ dout,
    const void* __restrict__ molf, const void* __restrict__ actf,
    const int* __restrict__ mode){
  const bool bf = (*mode != 0);
  int bid = blockIdx.x;                // BB*8 blocks
  int b = bid >> 3, g = bid & 7;
  int t = threadIdx.x;
  __shared__ float mf[FDIM];
  for (int f = t; f < FDIM; f += 256) mf[f] = ldf(molf, (size_t)b*FDIM+f, bf);
  __syncthreads();
  int sub = t >> 3;                    // 0..31 atom within group
  int j = t & 7;                       // lane within 8-thread team
  int l = g*32 + sub;
  size_t rb = ((size_t)b*LL + l)*FDIM;
  float s = 0.f;
  for (int c = j; c < 25; c += 8){     // chunks j, j+8, j+16, (j+24 if j==0)
    float v[8];
    ld8g(actf, rb + (size_t)c*8, bf, v);
    const float* xb = mf + c*8;
#pragma unroll
    for (int k = 0; k < 8; k++) s += v[k]*xb[k];
  }
  s += __shfl_down(s, 4, 8);
  s += __shfl_down(s, 2, 8);
  s += __shfl_down(s, 1, 8);
  if (j == 0) dout[(size_t)b*LL + l] = s;
}

// ---------- softmax over L (in-place on d buffer) ----------
__global__ __launch_bounds__(LL) void k_gitsoft(float* __restrict__ mw_out,
    const float* __restrict__ din){
  int b = blockIdx.x, l = threadIdx.x;
  __shared__ float red[LL];
  float d = din[(size_t)b*LL + l];
  red[l] = d; __syncthreads();
  for (int s = 128; s > 0; s >>= 1){ if (l < s) red[l] = fmaxf(red[l], red[l+s]); __syncthreads(); }
  float m = red[0]; __syncthreads();
  float e = __expf(d - m);
  red[l] = e; __syncthreads();
  for (int s = 128; s > 0; s >>= 1){ if (l < s) red[l] += red[l+s]; __syncthreads(); }
  mw_out[(size_t)b*LL + l] = e / red[0];
}

// ---------- act[row,f] = mw[row]*mol[b,f] + actf[row,f] ----------
__global__ __launch_bounds__(256) void k_gitwrite(unsigned short* __restrict__ act,
    const void* __restrict__ molf, const void* __restrict__ actf,
    const float* __restrict__ mw, const int* __restrict__ mode){
  const bool bf = (*mode != 0);
  int idx = blockIdx.x*256 + threadIdx.x;
  if (idx >= BL*25) return;
  int row = idx/25, f0 = (idx - row*25)*8;
  int b = row >> 8;
  float m = mw[row];
  float mv[8], av[8], v[8];
  ld8g(molf, (size_t)b*FDIM + f0, bf, mv);
  ld8g(actf, (size_t)row*FDIM + f0, bf, av);
#pragma unroll
  for (int j = 0; j < 8; j++) v[j] = m*mv[j] + av[j];
  st8(act + (size_t)row*FDIM + f0, v);
}

// ---------- attention elementwise, 8-wide: big[S'|P|Q'] stride 600 -> ctx ----------
__global__ __launch_bounds__(256) void k_attn_ew(const unsigned short* __restrict__ big,
    unsigned short* __restrict__ ctx, const int* __restrict__ adeg,
    int base, int total){
  int idx = blockIdx.x*256 + threadIdx.x;
  if (idx >= total) return;
  int a = idx/25, f0 = (idx - a*25)*8;
  int mb = (a >> 8) << 8;
  float s0[8];
  ld8(big + (size_t)a*600 + f0, s0);
  int4 d0 = *(const int4*)(adeg + (size_t)(base + a)*NN);
  int4 d1 = *(const int4*)(adeg + (size_t)(base + a)*NN + 4);
  int iv[NN] = {d0.x, d0.y, d0.z, d0.w, d1.x, d1.y, d1.z, d1.w};
  int nid[NN]; float nmul[NN], nadd[NN];
#pragma unroll
  for (int n = 0; n < NN; n++){
    nid[n] = mb + iv[n];
    bool pad = (iv[n] == LL-1);
    nmul[n] = pad ? 0.f : 1.f;
    nadd[n] = pad ? -9e8f : 0.f;
  }
  float e[NN][8], mx[8];
#pragma unroll
  for (int j = 0; j < 8; j++) mx[j] = -1e30f;
#pragma unroll
  for (int n = 0; n < NN; n++){
    float p[8];
    ld8(big + (size_t)nid[n]*600 + 200 + f0, p);
#pragma unroll
    for (int j = 0; j < 8; j++){
      float s = s0[j] + p[j];
      s = s > 0.f ? s : 0.01f*s;
      s += nadd[n];
      e[n][j] = s;
      mx[j] = fmaxf(mx[j], s);
    }
  }
  float sum[8] = {0,0,0,0,0,0,0,0};
#pragma unroll
  for (int n = 0; n < NN; n++)
#pragma unroll
    for (int j = 0; j < 8; j++){ e[n][j] = __expf(e[n][j] - mx[j]); sum[j] += e[n][j]; }
  float acc[8] = {0,0,0,0,0,0,0,0};
#pragma unroll
  for (int n = 0; n < NN; n++){
    float q[8];
    ld8(big + (size_t)nid[n]*600 + 400 + f0, q);
#pragma unroll
    for (int j = 0; j < 8; j++) acc[j] += e[n][j]*nmul[n]*q[j];
  }
  float o[8];
#pragma unroll
  for (int j = 0; j < 8; j++) o[j] = elu_(acc[j]/sum[j]);
  st8(ctx + (size_t)a*FDIM + f0, o);
}

// ---------- merged decode: 4 atoms/block (biases pre-folded into big) ----------
__global__ __launch_bounds__(256) void k_dec(const unsigned short* __restrict__ big,
    const int* __restrict__ adeg, void* __restrict__ out, int base,
    const int* __restrict__ mode){
  const bool bf = (*mode != 0);
  const size_t obase = (size_t)BL*AOUTD;
  int sub = threadIdx.x >> 6, tl = threadIdx.x & 63;
  int a = blockIdx.x*4 + sub;
  __shared__ float al[4][40];
  __shared__ float sm[4][4], ss[4][4];
  const int lo[4] = {0,16,24,31}, hi[4] = {16,22,30,36};
  if (tl < AOUTD) al[sub][tl] = bf2f(big[(size_t)a*64 + tl]);
  __syncthreads();
  if (tl < 4){
    float m = -1e30f;
    for (int k = lo[tl]; k < hi[tl]; k++) m = fmaxf(m, al[sub][k]);
    float s = 0.f;
    for (int k = lo[tl]; k < hi[tl]; k++) s += __expf(al[sub][k]-m);
    sm[sub][tl] = m; ss[sub][tl] = s;
  }
  __syncthreads();
  if (tl < AOUTD){
    float v = 0.f;
#pragma unroll
    for (int g = 0; g < 4; g++)
      if (tl >= lo[g] && tl < hi[g]) v += __expf(al[sub][tl]-sm[sub][g])/ss[sub][g];
    if (tl == 24) v += fmaxf(al[sub][24], 0.f);
    if (tl == 30 || tl == 36 || tl == 37 || tl == 38) v += sigm(al[sub][tl]);
    stf(out, (size_t)(base + a)*AOUTD + tl, v, bf);
  } else if (tl >= 40 && tl < 48){
    int n = tl - 40;
    int iv = adeg[((size_t)(base + a))*NN + n];
    int vr = ((a >> 8) << 8) + iv;
    float bl[BOUTD];
#pragma unroll
    for (int o = 0; o < BOUTD; o++)
      bl[o] = bf2f(big[(size_t)a*64 + 40 + o]) + bf2f(big[(size_t)vr*64 + 50 + o]);
    float v[BOUTD];
    float m0 = fmaxf(fmaxf(bl[0],bl[1]), fmaxf(bl[2],bl[3]));
    float e0[4], s0 = 0.f;
#pragma unroll
    for (int j = 0; j < 4; j++){ e0[j] = __expf(bl[j]-m0); s0 += e0[j]; }
    float m1 = fmaxf(fmaxf(bl[6],bl[7]), fmaxf(bl[8],bl[9]));
    float e1[4], s1 = 0.f;
#pragma unroll
    for (int j = 0; j < 4; j++){ e1[j] = __expf(bl[6+j]-m1); s1 += e1[j]; }
#pragma unroll
    for (int j = 0; j < 4; j++) v[j] = e0[j]/s0;
    v[4] = sigm(bl[4]); v[5] = sigm(bl[5]);
#pragma unroll
    for (int j = 0; j < 4; j++) v[6+j] = e1[j]/s1;
    size_t op = obase + ((size_t)(base + a)*NN + n)*BOUTD;
#pragma unroll
    for (int j = 0; j < BOUTD; j++) stf(out, op + j, v[j], bf);
  }
}

extern "C" void kernel_launch(void* const* d_in, const int* in_sizes, int n_in,
                              void* d_out, int out_size, void* d_ws, size_t ws_size,
                              hipStream_t stream) {
  const int* adeg = (const int*)d_in[2];
  const void* amask = d_in[4];
  const void* molf = d_in[5];
  const void* actf = d_in[6];
  const void* afw = d_in[7];  const void* afb = d_in[8];
  const void* bfw = d_in[9];  const void* bfb = d_in[10];
  const void* alw = d_in[11]; const void* alb = d_in[12];
  const void* atw = d_in[13]; const void* atb = d_in[14];
  const void* gwih = d_in[15]; const void* gwhh = d_in[16];
  const void* gbih = d_in[17]; const void* gbhh = d_in[18];
  const void* maw = d_in[19]; const void* mab = d_in[20];
  const void* mwih = d_in[21]; const void* mwhh = d_in[22];
  const void* mbih = d_in[23]; const void* mbhh = d_in[24];

  // ---- ws layout: act0 | act1 | mw | pre | wrep | bt | mode | ctx[CH] | big[CH,600] ----
  char* w = (char*)d_ws;
  unsigned short* act0 = (unsigned short*)w;  w += (size_t)BL*FDIM*2;           // 13.11 MB
  unsigned short* act1 = (unsigned short*)w;  w += (size_t)BL*FDIM*2;           // 13.11 MB
  float*          mw   = (float*)w;           w += (size_t)BL*4;
  float*          pre  = (float*)w;           w += (size_t)BB*FDIM*4;
  unsigned short* wrep = (unsigned short*)w;  w += (size_t)WCHUNKS*16;          // 2.81 MB
  float*          bt   = (float*)w;           w += (size_t)NBIAS*4;
  int*            mode = (int*)w;             w += 16;
  size_t fixed = (size_t)(w - (char*)d_ws);
  int CH = 8192;
  if (ws_size >= fixed + (size_t)32768*1600) CH = 32768;
  else if (ws_size >= fixed + (size_t)16384*1600) CH = 16384;
  unsigned short* ctx = (unsigned short*)w;   w += (size_t)CH*FDIM*2;
  unsigned short* big = (unsigned short*)w;                                     // [CH][600]
  const int NCH = BL / CH;
  const int EWT = CH*25, EWB = EWT/256;
  const int GY = CH/128;           // row-tiles per chunk (divisible by 8)

  k_probe<<<1, 64, 0, stream>>>((const unsigned int*)amask, mode);
  k_repack<<<(WCHUNKS + 255)/256, 256, 0, stream>>>(wrep, maw, mwih, mwhh,
      alw, atw, gwih, gwhh, afw, bfw, mode);
  k_biases<<<(NBIAS + 255)/256, 256, 0, stream>>>(bt, mbhh, mbih, alb, atb,
      gbhh, gbih, afb, bfb, mode);
  k_premol<<<BB, 256, 0, stream>>>(pre, molf, maw, mab, mode);
  k_gitdot2<<<BB*8, 256, 0, stream>>>(mw, molf, actf, mode);
  k_gitsoft<<<BB, LL, 0, stream>>>(mw, mw);
  k_gitwrite<<<(BL*25 + 255)/256, 256, 0, stream>>>(act0, molf, actf, mw, mode);

  unsigned short* cur = act0;
  unsigned short* alt = act1;

  // ---- mol GRU x2: ctx GEMM -> fully-fused GRU (gi+gh+update) ----
  for (int ts = 0; ts < 2; ts++){
    for (int c = 0; c < NCH; c++){
      int base = c*CH;
      unsigned short* Ac = cur + (size_t)base*FDIM;
      k_gemm<<<4*GY, 256, 0, stream>>>(Ac, wrep + (size_t)P1C*8, 256, 4,
          ctx, FDIM, FDIM, 2, pre, base);                                       // ctx = elu(pre+.)
      k_gru2<<<13*GY, 256, 0, stream>>>(ctx, Ac, alt + (size_t)base*FDIM,
          wrep + (size_t)PMG*8, bt + 600, bt + 0, (ts==1));
    }
    { unsigned short* tmp = cur; cur = alt; alt = tmp; }
  }
  // ---- 2 attention+GRU rounds ----
  for (int d = 0; d < 2; d++){
    size_t pA = (d ? PA1 : PA0), pG = (d ? PG1 : PG0);
    float* btA = bt + 1200 + d*1800;          // alb|0|atb (600 entries)
    float* gib = bt + 2400 + d*1800;          // gbih
    float* ghb = bt + 1800 + d*1800;          // gbhh
    for (int c = 0; c < NCH; c++){
      int base = c*CH;
      unsigned short* Ac = cur + (size_t)base*FDIM;
      k_gemm<<<10*GY, 256, 0, stream>>>(Ac, wrep + pA*8, 640, 10,
          big, 600, 600, 1, btA, 0);                                            // S'|P|Q'
      k_attn_ew<<<EWB, 256, 0, stream>>>(big, ctx, adeg, base, EWT);
      k_gru2<<<13*GY, 256, 0, stream>>>(ctx, Ac, alt + (size_t)base*FDIM,
          wrep + pG*8, gib, ghb, 1);
    }
    { unsigned short* tmp = cur; cur = alt; alt = tmp; }
  }
  // ---- decode (cur == act0 after 4 swaps) ----
  for (int c = 0; c < NCH; c++){
    int base = c*CH;
    unsigned short* Ac = cur + (size_t)base*FDIM;
    k_gemm<<<1*GY, 256, 0, stream>>>(Ac, wrep + (size_t)PD*8, 128, 1,
        big, 64, 64, 1, bt + 4800, 0);                                          // AL|U|V (+afb,bfb)
    k_dec<<<CH/4, 256, 0, stream>>>(big, adeg, d_out, base, mode);
  }
}